// Round 5
// baseline (1561.799 us; speedup 1.0000x reference)
//
#include <hip/hip_runtime.h>

#define BB 8192
#define TT 20
#define HH 128
#define H4 512
#define KC 5
#define R 16          // batch rows per block
#define NT 256
#define NBLK (BB/R)   // 512 blocks

typedef unsigned short u16;
typedef float v4f __attribute__((ext_vector_type(4)));
typedef short v8s __attribute__((ext_vector_type(8)));

// output segment offsets (elements)
#define GY_OFF (BB*TT*30)
#define GF_OFF (GY_OFF + BB*TT*15)
#define GFA_OFF (GF_OFF + BB*TT*15)

// ws layout (u16 elements): swizzled bf16 hi/lo B-operands
#define UMY_HI 0
#define UMY_LO 65536
#define UFF_HI 131072
#define UFF_LO 196608
#define WHMY_HI 262144
#define WHMY_LO (WHMY_HI + 6144)
#define WHFF_HI (WHMY_HI + 12288)
#define WHFF_LO (WHFF_HI + 4096)
#define PREP_N (131072 + 6144 + 4096)   // source elements to prep

__device__ __forceinline__ float bf2f(u16 u){
    union { unsigned int i; float f; } x; x.i = ((unsigned int)u) << 16; return x.f;
}
__device__ __forceinline__ u16 f2bf(float f){
    union { float f; unsigned int i; } x; x.f = f;
    unsigned int i = x.i;
    return (u16)((i + 0x7FFFu + ((i >> 16) & 1u)) >> 16);
}
__device__ __forceinline__ float sigm(float x){ return 1.0f / (1.0f + __expf(-x)); }
__device__ __forceinline__ float tanh_(float x){
    x = fminf(10.0f, fmaxf(-10.0f, x));
    float e = __expf(2.0f * x);
    return (e - 1.0f) / (e + 1.0f);
}

#define AM0 0.3f
#define AM1 0.1f
#define AO  0.3f

// ---- prep: swizzle U_my/U_ff/Wh_my/Wh_ff into MFMA B-frag bf16 hi/lo ----
// B-frag layout for 16x16x32: lane L holds B[k=(L>>4)*8+j][n=L&15], j=0..7.
// chunk (ctile c, kblock q): elem ((c*4+q)*64 + L)*8 + j
__global__ void prep_kernel(const float* __restrict__ U_my, const float* __restrict__ U_ff,
                            const float* __restrict__ Wh_my, const float* __restrict__ Wh_ff,
                            u16* __restrict__ ws)
{
    int t = blockIdx.x * 256 + threadIdx.x;
    if (t >= PREP_N) return;
    if (t < 131072){
        int m = t >> 16, e = t & 65535;
        int j = e & 7, L = (e >> 3) & 63, q = (e >> 9) & 3, c = e >> 11;
        int k   = q*32 + ((L >> 4) << 3) + j;
        int col = (c << 4) + (L & 15);
        float v = (m ? U_ff : U_my)[k*H4 + col];
        u16 hi = f2bf(v); u16 lo = f2bf(v - bf2f(hi));
        int base = m ? UFF_HI : UMY_HI;
        ws[base + e] = hi; ws[base + 65536 + e] = lo;
    } else if (t < 131072 + 6144){
        int e = t - 131072;
        int j = e & 7, L = (e >> 3) & 63, q = (e >> 9) & 3, c = e >> 11;  // c 0..2
        int k   = q*32 + ((L >> 4) << 3) + j;
        int col = (c << 4) + (L & 15);
        float v = (col < 45) ? Wh_my[k*45 + col] : 0.0f;
        u16 hi = f2bf(v); u16 lo = f2bf(v - bf2f(hi));
        ws[WHMY_HI + e] = hi; ws[WHMY_LO + e] = lo;
    } else {
        int e = t - 131072 - 6144;
        int j = e & 7, L = (e >> 3) & 63, q = (e >> 9) & 3, c = e >> 11;  // c 0..1
        int k   = q*32 + ((L >> 4) << 3) + j;
        int col = (c << 4) + (L & 15);
        float v = (col < 30) ? Wh_ff[k*30 + col] : 0.0f;
        u16 hi = f2bf(v); u16 lo = f2bf(v - bf2f(hi));
        ws[WHFF_HI + e] = hi; ws[WHFF_LO + e] = lo;
    }
}

__global__ __launch_bounds__(NT, 2) void decoder_kernel(
    const float* __restrict__ cond_m, const float* __restrict__ cond_y,
    const float* __restrict__ cond_f, const float* __restrict__ cond_fa,
    const float* __restrict__ state_h, const float* __restrict__ state_c,
    const float* __restrict__ W_my, const float* __restrict__ b_my,
    const float* __restrict__ W_ff, const float* __restrict__ b_ff,
    const float* __restrict__ bh_my, const float* __restrict__ bh_ff,
    const float* __restrict__ gum, const float* __restrict__ znorm,
    const u16* __restrict__ ws, float* __restrict__ out)
{
    __shared__ float s_z[R][516];                    // MFMA z output / enc scratch
    __shared__ u16 s_hm_hi[R][136], s_hm_lo[R][136]; // h_my split-bf16, [r][k]
    __shared__ u16 s_hf_hi[R][136], s_hf_lo[R][136];
    __shared__ float s_r[R][76];
    __shared__ float s_red[R][8];
    __shared__ float s_c5[R][5], s_c2[R][2];

    const int tid  = threadIdx.x;
    const int lane = tid & 63, wid = tid >> 6;
    const int quad = lane >> 4, l15 = lane & 15;
    const int j    = tid & 127, rblk = (tid >> 7) * 8;
    const int row0 = blockIdx.x * R;

    // ---- init: enc_h fp32 into s_z scratch + split-bf16 h arrays ----
    for (int p = tid; p < R*HH; p += NT){
        int r = p >> 7, k = p & 127;
        float v = state_h[(row0 + r)*HH + k];
        s_z[r][k] = v;
        u16 hi = f2bf(v), lo = f2bf(v - bf2f(hi));
        s_hm_hi[r][k] = hi; s_hm_lo[r][k] = lo;
        s_hf_hi[r][k] = hi; s_hf_lo[r][k] = lo;
    }
    if (tid < R){
        int b = row0 + tid;
        float m0 = cond_m[(b*TT)*2 + 0];
        float m1 = cond_m[(b*TT)*2 + 1];
        float y0 = cond_y[b*TT];
        float f0 = cond_f[b*TT];
        float fa0= cond_fa[b*TT];
        s_c5[tid][0]=m0; s_c5[tid][1]=m1; s_c5[tid][2]=y0; s_c5[tid][3]=f0; s_c5[tid][4]=fa0;
        s_c2[tid][0]=f0; s_c2[tid][1]=fa0;
    }
    __syncthreads();

    // ---- one-time: pre = enc_h @ W[:128] + b (VALU), c regs ----
    float pm[4][8], pf[4][8];
    #pragma unroll
    for (int g = 0; g < 4; g++){
        float bm = b_my[j + g*HH], bf = b_ff[j + g*HH];
        #pragma unroll
        for (int r8 = 0; r8 < 8; r8++){ pm[g][r8] = bm; pf[g][r8] = bf; }
    }
    for (int k = 0; k < HH; k++){
        const float* wm = W_my + k*H4 + j;
        const float* wf = W_ff + k*H4 + j;
        float wm0 = wm[0], wm1 = wm[HH], wm2 = wm[2*HH], wm3 = wm[3*HH];
        float wf0 = wf[0], wf1 = wf[HH], wf2 = wf[2*HH], wf3 = wf[3*HH];
        #pragma unroll
        for (int r8 = 0; r8 < 8; r8++){
            float e = s_z[rblk + r8][k];
            pm[0][r8] = fmaf(e, wm0, pm[0][r8]);
            pm[1][r8] = fmaf(e, wm1, pm[1][r8]);
            pm[2][r8] = fmaf(e, wm2, pm[2][r8]);
            pm[3][r8] = fmaf(e, wm3, pm[3][r8]);
            pf[0][r8] = fmaf(e, wf0, pf[0][r8]);
            pf[1][r8] = fmaf(e, wf1, pf[1][r8]);
            pf[2][r8] = fmaf(e, wf2, pf[2][r8]);
            pf[3][r8] = fmaf(e, wf3, pf[3][r8]);
        }
    }
    float c_my[8], c_ff[8];
    #pragma unroll
    for (int r8 = 0; r8 < 8; r8++){
        float cv = state_c[(row0 + rblk + r8)*HH + j];
        c_my[r8] = cv; c_ff[r8] = cv;
    }
    __syncthreads();   // s_z now free for MFMA output

    // ---- MFMA: z(16x512) = h(16x128) @ U, 3-term split-bf16 ----
    auto lstm_mfma = [&](const u16 (*hhi)[136], const u16 (*hlo)[136], int ubase){
        v4f acc[8];
        #pragma unroll
        for (int i = 0; i < 8; i++) acc[i] = (v4f){0.f,0.f,0.f,0.f};
        #pragma unroll
        for (int q = 0; q < 4; q++){
            int k0 = q*32 + quad*8;
            v8s ahi = *(const v8s*)&hhi[l15][k0];
            v8s alo = *(const v8s*)&hlo[l15][k0];
            #pragma unroll
            for (int i = 0; i < 8; i++){
                int c = wid*8 + i;
                const u16* bp = ws + ubase + ((c*4 + q)*64 + lane)*8;
                v8s bhi = *(const v8s*)bp;
                v8s blo = *(const v8s*)(bp + 65536);
                acc[i] = __builtin_amdgcn_mfma_f32_16x16x32_bf16(ahi, bhi, acc[i], 0,0,0);
                acc[i] = __builtin_amdgcn_mfma_f32_16x16x32_bf16(ahi, blo, acc[i], 0,0,0);
                acc[i] = __builtin_amdgcn_mfma_f32_16x16x32_bf16(alo, bhi, acc[i], 0,0,0);
            }
        }
        #pragma unroll
        for (int i = 0; i < 8; i++){
            int cb = (wid*8 + i)*16 + l15;
            #pragma unroll
            for (int v = 0; v < 4; v++) s_z[quad*4 + v][cb] = acc[i][v];
        }
    };

    // ---- gates: z += cond@Wc (+pre), nonlinear, write split-bf16 h ----
    auto gate_phase = [&](const float* Wc, int ncond, const float* scnd, int ldc,
                          float (*pre)[8], float* cst, u16 (*dhi)[136], u16 (*dlo)[136]){
        float z[4][8];
        #pragma unroll
        for (int g = 0; g < 4; g++)
            #pragma unroll
            for (int r8 = 0; r8 < 8; r8++)
                z[g][r8] = pre[g][r8] + s_z[rblk + r8][j + g*HH];
        for (int k = 0; k < ncond; k++){
            const float* w = Wc + k*H4 + j;
            float w0 = w[0], w1 = w[HH], w2 = w[2*HH], w3 = w[3*HH];
            #pragma unroll
            for (int r8 = 0; r8 < 8; r8++){
                float cv = scnd[(rblk + r8)*ldc + k];
                z[0][r8] = fmaf(cv, w0, z[0][r8]);
                z[1][r8] = fmaf(cv, w1, z[1][r8]);
                z[2][r8] = fmaf(cv, w2, z[2][r8]);
                z[3][r8] = fmaf(cv, w3, z[3][r8]);
            }
        }
        #pragma unroll
        for (int r8 = 0; r8 < 8; r8++){
            float c2 = sigm(z[1][r8])*cst[r8] + sigm(z[0][r8])*tanh_(z[2][r8]);
            cst[r8] = c2;
            float h = sigm(z[3][r8])*tanh_(c2);
            u16 hi = f2bf(h);
            dhi[rblk + r8][j] = hi;
            dlo[rblk + r8][j] = f2bf(h - bf2f(hi));
        }
    };

    // ---- heads via MFMA: one 16-col tile ----
    auto head_tile = [&](int c, int whbase, int looff,
                         const u16 (*hhi)[136], const u16 (*hlo)[136],
                         const float* bh, int ncol, int rbase){
        v4f acc = (v4f){0.f,0.f,0.f,0.f};
        #pragma unroll
        for (int q = 0; q < 4; q++){
            int k0 = q*32 + quad*8;
            v8s ahi = *(const v8s*)&hhi[l15][k0];
            v8s alo = *(const v8s*)&hlo[l15][k0];
            const u16* bp = ws + whbase + ((c*4 + q)*64 + lane)*8;
            v8s bhi = *(const v8s*)bp;
            v8s blo = *(const v8s*)(bp + looff);
            acc = __builtin_amdgcn_mfma_f32_16x16x32_bf16(ahi, bhi, acc, 0,0,0);
            acc = __builtin_amdgcn_mfma_f32_16x16x32_bf16(ahi, blo, acc, 0,0,0);
            acc = __builtin_amdgcn_mfma_f32_16x16x32_bf16(alo, bhi, acc, 0,0,0);
        }
        int gc = c*16 + l15;
        if (gc < ncol){
            float bias = bh[gc];
            #pragma unroll
            for (int v = 0; v < 4; v++) s_r[quad*4 + v][rbase + gc] = acc[v] + bias;
        }
    };

    const float* Wc_my = W_my + HH*H4;   // cond rows 128..132
    const float* Wc_ff = W_ff + HH*H4;   // cond rows 128..129

    for (int t = 0; t < TT; t++){
        lstm_mfma(s_hm_hi, s_hm_lo, UMY_HI);
        __syncthreads();
        gate_phase(Wc_my, 5, &s_c5[0][0], 5, pm, c_my, s_hm_hi, s_hm_lo);
        __syncthreads();
        lstm_mfma(s_hf_hi, s_hf_lo, UFF_HI);
        __syncthreads();
        gate_phase(Wc_ff, 2, &s_c2[0][0], 2, pf, c_ff, s_hf_hi, s_hf_lo);
        __syncthreads();

        // heads: 3 my ctiles (45 cols) + 2 ff ctiles (30 cols)
        if (wid < 3) head_tile(wid, WHMY_HI, 6144, s_hm_hi, s_hm_lo, bh_my, 45, 0);
        else         head_tile(0,   WHFF_HI, 4096, s_hf_hi, s_hf_lo, bh_ff, 30, 45);
        if (wid == 0) head_tile(1,  WHFF_HI, 4096, s_hf_hi, s_hf_lo, bh_ff, 30, 45);
        __syncthreads();

        // softmax reductions: 16 rows x 4 groups
        if (tid < R*4){
            int r = tid >> 2, g = tid & 3;
            int base = (g==0) ? 0 : (g==1) ? 30 : (g==2) ? 45 : 60;
            float m = s_r[r][base];
            #pragma unroll
            for (int k = 1; k < KC; k++) m = fmaxf(m, s_r[r][base+k]);
            float s = 0.f;
            #pragma unroll
            for (int k = 0; k < KC; k++) s += __expf(s_r[r][base+k] - m);
            s_red[r][2*g] = m; s_red[r][2*g+1] = 1.0f / s;
        }
        __syncthreads();

        // outputs (fp32)
        for (int idx = tid; idx < R*75; idx += NT){
            int r = idx / 75, q = idx % 75;
            int b = row0 + r;
            float v; int dst;
            if (q < 30){
                float x = s_r[r][q];
                if (q < 5)       v = __expf(x - s_red[r][0]) * s_red[r][1];
                else if (q < 10) v = x;
                else if (q < 15) v = __expf(x);
                else if (q < 20) v = x;
                else if (q < 25) v = __expf(x);
                else             v = tanh_(x);
                dst = (b*TT + t)*30 + q;
            } else if (q < 45){
                int q2 = q - 30; float x = s_r[r][30 + q2];
                v = (q2 < 5) ? __expf(x - s_red[r][2]) * s_red[r][3]
                             : (q2 < 10) ? x : __expf(x);
                dst = GY_OFF + (b*TT + t)*15 + q2;
            } else if (q < 60){
                int q2 = q - 45; float x = s_r[r][45 + q2];
                v = (q2 < 5) ? __expf(x - s_red[r][4]) * s_red[r][5]
                             : (q2 < 10) ? x : __expf(x);
                dst = GF_OFF + (b*TT + t)*15 + q2;
            } else {
                int q2 = q - 60; float x = s_r[r][60 + q2];
                v = (q2 < 5) ? __expf(x - s_red[r][6]) * s_red[r][7]
                             : (q2 < 10) ? x : __expf(x);
                dst = GFA_OFF + (b*TT + t)*15 + q2;
            }
            out[dst] = v;
        }

        // sampling + next cond
        if (tid < R){
            int r = tid, b = row0 + r;
            int tn = (t + 1 < TT) ? t + 1 : TT - 1;
            const float* Rr = s_r[r];
            const float* g0 = gum + ((t*4 + 0)*BB + b)*KC;
            const float* g1 = gum + ((t*4 + 1)*BB + b)*KC;
            const float* g2 = gum + ((t*4 + 2)*BB + b)*KC;
            const float* g3 = gum + ((t*4 + 3)*BB + b)*KC;
            const float* zn = znorm + (t*BB + b)*5;

            int im = 0;  { float bv = Rr[0] + g0[0];
                for (int k = 1; k < KC; k++){ float v = Rr[k] + g0[k]; if (v > bv){ bv = v; im = k; } } }
            int iy = 0;  { float bv = Rr[30] + g1[0];
                for (int k = 1; k < KC; k++){ float v = Rr[30+k] + g1[k]; if (v > bv){ bv = v; iy = k; } } }
            int if_ = 0; { float bv = Rr[45] + g2[0];
                for (int k = 1; k < KC; k++){ float v = Rr[45+k] + g2[k]; if (v > bv){ bv = v; if_ = k; } } }
            int ifa = 0; { float bv = Rr[60] + g3[0];
                for (int k = 1; k < KC; k++){ float v = Rr[60+k] + g3[k]; if (v > bv){ bv = v; ifa = k; } } }

            float z1 = zn[0], z2 = zn[1];
            float rv   = tanh_(Rr[25 + im]);
            float slon = Rr[5 + im]  + __expf(Rr[10 + im]) * z1;
            float slat = Rr[15 + im] + __expf(Rr[20 + im]) *
                         (rv*z1 + sqrtf(fmaxf(0.f, 1.f - rv*rv))*z2);
            float sy  = Rr[35 + iy]  + __expf(Rr[40 + iy])  * zn[2];
            float sf  = Rr[50 + if_] + __expf(Rr[55 + if_]) * zn[3];
            float sfa = Rr[65 + ifa] + __expf(Rr[70 + ifa]) * zn[4];

            float nm0 = cond_m[(b*TT + tn)*2 + 0];
            float nm1 = cond_m[(b*TT + tn)*2 + 1];
            float ny  = cond_y[b*TT + tn];
            float nf  = cond_f[b*TT + tn];
            float nfa = cond_fa[b*TT + tn];

            float cm0 = (fabsf(slon - nm0) < AM0) ? slon : nm0;
            float cm1 = (fabsf(slat - nm1) < AM1) ? slat : nm1;
            float cy  = (fabsf(sy  - ny ) < AO ) ? sy  : ny;
            float cf  = (fabsf(sf  - nf ) < AO ) ? sf  : nf;
            float cfa = (fabsf(sfa - nfa) < AO ) ? sfa : nfa;

            s_c5[r][0] = cm0; s_c5[r][1] = cm1; s_c5[r][2] = cy;
            s_c5[r][3] = cf;  s_c5[r][4] = cfa;
            s_c2[r][0] = cf;  s_c2[r][1] = cfa;
        }
        __syncthreads();
    }
}

extern "C" void kernel_launch(void* const* d_in, const int* in_sizes, int n_in,
                              void* d_out, int out_size, void* d_ws, size_t ws_size,
                              hipStream_t stream)
{
    (void)in_sizes; (void)n_in; (void)ws_size; (void)out_size;
    const float* cond_m  = (const float*)d_in[0];
    const float* cond_y  = (const float*)d_in[1];
    const float* cond_f  = (const float*)d_in[2];
    const float* cond_fa = (const float*)d_in[3];
    const float* state_h = (const float*)d_in[4];
    const float* state_c = (const float*)d_in[5];
    const float* W_my    = (const float*)d_in[6];
    const float* U_my    = (const float*)d_in[7];
    const float* b_my    = (const float*)d_in[8];
    const float* W_ff    = (const float*)d_in[9];
    const float* U_ff    = (const float*)d_in[10];
    const float* b_ff    = (const float*)d_in[11];
    const float* Wh_my   = (const float*)d_in[12];
    const float* bh_my   = (const float*)d_in[13];
    const float* Wh_ff   = (const float*)d_in[14];
    const float* bh_ff   = (const float*)d_in[15];
    const float* gum     = (const float*)d_in[16];
    const float* znorm   = (const float*)d_in[17];
    u16* ws = (u16*)d_ws;
    float* out = (float*)d_out;

    prep_kernel<<<(PREP_N + 255)/256, 256, 0, stream>>>(U_my, U_ff, Wh_my, Wh_ff, ws);
    decoder_kernel<<<NBLK, NT, 0, stream>>>(
        cond_m, cond_y, cond_f, cond_fa, state_h, state_c,
        W_my, b_my, W_ff, b_ff, bh_my, bh_ff, gum, znorm, ws, out);
}

// Round 6
// 517.978 us; speedup vs baseline: 3.0152x; 3.0152x over previous
//
#include <hip/hip_runtime.h>

#define BB 8192
#define TT 20
#define HH 128
#define H4 512
#define KC 5
#define R 32
#define NT 512
#define NBLK (BB/R)   // 256 blocks = 1 per CU

typedef _Float16 f16;
typedef float v4f __attribute__((ext_vector_type(4)));
typedef _Float16 v8h __attribute__((ext_vector_type(8)));

// output segment offsets (elements)
#define GY_OFF (BB*TT*30)
#define GF_OFF (GY_OFF + BB*TT*15)
#define GFA_OFF (GF_OFF + BB*TT*15)

// ws offsets in f16 units
#define UMY_O   0          // U_my fp16 hi, permuted cols (65536)
#define UFF_O   65536
#define WMYH_O  131072     // W_my[:128] fp16 hi, permuted (65536)
#define WMYL_O  196608     // fp16 lo
#define WFFH_O  262144
#define WFFL_O  327680
#define WHMY_O  393216     // Wh_my hi, unpermuted (6144)
#define WHFF_O  399360     // Wh_ff hi (4096)
#define PREP_N  272384

__device__ __forceinline__ float sigm(float x){ return 1.0f / (1.0f + __expf(-x)); }
__device__ __forceinline__ float tanh_(float x){
    x = fminf(10.0f, fmaxf(-10.0f, x));
    float e = __expf(2.0f * x);
    return (e - 1.0f) / (e + 1.0f);
}

#define AM0 0.3f
#define AM1 0.1f
#define AO  0.3f

// B-frag (16x16x32): lane L holds B[k=(L>>4)*8+jj][n=L&15], jj=0..7.
// elem index e = ((c*4+q)*64 + L)*8 + jj.  U/W col-permutation: tile c -> gate=c&3,
// unit base=((c>>2)<<4), so orig col = (c&3)*128 + ((c>>2)<<4) + (L&15).
__global__ void prep_kernel(const float* __restrict__ U_my, const float* __restrict__ U_ff,
                            const float* __restrict__ W_my, const float* __restrict__ W_ff,
                            const float* __restrict__ Wh_my, const float* __restrict__ Wh_ff,
                            f16* __restrict__ ws)
{
    int t = blockIdx.x * 256 + threadIdx.x;
    if (t >= PREP_N) return;
    if (t < 131072){
        int m = t >> 16, e = t & 65535;
        int jj = e & 7, L = (e >> 3) & 63, q = (e >> 9) & 3, c = e >> 11;
        int k   = q*32 + ((L >> 4) << 3) + jj;
        int col = (c & 3)*HH + ((c >> 2) << 4) + (L & 15);
        float v = (m ? U_ff : U_my)[k*H4 + col];
        ws[(m ? UFF_O : UMY_O) + e] = (f16)v;
    } else if (t < 262144){
        int m = (t - 131072) >> 16, e = t & 65535;
        int jj = e & 7, L = (e >> 3) & 63, q = (e >> 9) & 3, c = e >> 11;
        int k   = q*32 + ((L >> 4) << 3) + jj;
        int col = (c & 3)*HH + ((c >> 2) << 4) + (L & 15);
        float v = (m ? W_ff : W_my)[k*H4 + col];
        f16 hi = (f16)v;
        f16 lo = (f16)(v - (float)hi);
        ws[(m ? WFFH_O : WMYH_O) + e] = hi;
        ws[(m ? WFFL_O : WMYL_O) + e] = lo;
    } else if (t < 262144 + 6144){
        int e = t - 262144;
        int jj = e & 7, L = (e >> 3) & 63, q = (e >> 9) & 3, c = e >> 11;   // c 0..2
        int k   = q*32 + ((L >> 4) << 3) + jj;
        int col = (c << 4) + (L & 15);
        float v = (col < 45) ? Wh_my[k*45 + col] : 0.0f;
        ws[WHMY_O + e] = (f16)v;
    } else {
        int e = t - 262144 - 6144;
        int jj = e & 7, L = (e >> 3) & 63, q = (e >> 9) & 3, c = e >> 11;   // c 0..1
        int k   = q*32 + ((L >> 4) << 3) + jj;
        int col = (c << 4) + (L & 15);
        float v = (col < 30) ? Wh_ff[k*30 + col] : 0.0f;
        ws[WHFF_O + e] = (f16)v;
    }
}

__global__ __launch_bounds__(NT, 2) void decoder_kernel(
    const float* __restrict__ cond_m, const float* __restrict__ cond_y,
    const float* __restrict__ cond_f, const float* __restrict__ cond_fa,
    const float* __restrict__ state_h, const float* __restrict__ state_c,
    const float* __restrict__ W_my, const float* __restrict__ b_my,
    const float* __restrict__ W_ff, const float* __restrict__ b_ff,
    const float* __restrict__ bh_my, const float* __restrict__ bh_ff,
    const float* __restrict__ gum, const float* __restrict__ znorm,
    const f16* __restrict__ ws, float* __restrict__ out)
{
    __shared__ f16 s_hm_hi[R][136], s_hm_lo[R][136];   // h split-fp16, [row][k]
    __shared__ f16 s_hf_hi[R][136], s_hf_lo[R][136];
    __shared__ float s_wcm[5][H4], s_wcf[2][H4];       // cond rows of W (orig layout)
    __shared__ float s_r[R][76];
    __shared__ float s_red[R][8];
    __shared__ float s_c5[R][5], s_c2[R][2];

    const int tid  = threadIdx.x;
    const int lane = tid & 63, w = tid >> 6;           // 8 waves
    const int quad = lane >> 4, l15 = lane & 15;
    const int jcol = (w << 4) + l15;                   // this lane's hidden unit
    const int row0 = blockIdx.x * R;

    // ---- init LDS ----
    for (int p = tid; p < R*HH; p += NT){
        int r = p >> 7, k = p & 127;
        float v = state_h[(row0 + r)*HH + k];
        f16 hi = (f16)v, lo = (f16)(v - (float)hi);
        s_hm_hi[r][k] = hi; s_hm_lo[r][k] = lo;
        s_hf_hi[r][k] = hi; s_hf_lo[r][k] = lo;
    }
    for (int p = tid; p < 5*H4; p += NT) s_wcm[p >> 9][p & 511] = W_my[(HH + (p >> 9))*H4 + (p & 511)];
    for (int p = tid; p < 2*H4; p += NT) s_wcf[p >> 9][p & 511] = W_ff[(HH + (p >> 9))*H4 + (p & 511)];
    if (tid < R){
        int b = row0 + tid;
        float m0 = cond_m[(b*TT)*2 + 0], m1 = cond_m[(b*TT)*2 + 1];
        float y0 = cond_y[b*TT], f0 = cond_f[b*TT], fa0 = cond_fa[b*TT];
        s_c5[tid][0]=m0; s_c5[tid][1]=m1; s_c5[tid][2]=y0; s_c5[tid][3]=f0; s_c5[tid][4]=fa0;
        s_c2[tid][0]=f0; s_c2[tid][1]=fa0;
    }

    // c-state in registers: index [rt*4+v] -> row rt*16+quad*4+v, unit jcol
    float c_my[8], c_ff[8];
    #pragma unroll
    for (int rt = 0; rt < 2; rt++)
        #pragma unroll
        for (int v = 0; v < 4; v++){
            int row = rt*16 + quad*4 + v;
            float cv = state_c[(row0 + row)*HH + jcol];
            c_my[rt*4+v] = cv; c_ff[rt*4+v] = cv;
        }
    __syncthreads();

    // ---- one-time: pre = enc_h @ W[:128] + b via 3-term fp16 MFMA (C-layout regs) ----
    v4f pre_m[4][2], pre_f[4][2];
    #pragma unroll
    for (int ci = 0; ci < 4; ci++){
        #pragma unroll
        for (int rt = 0; rt < 2; rt++){ pre_m[ci][rt] = (v4f){0,0,0,0}; pre_f[ci][rt] = (v4f){0,0,0,0}; }
        #pragma unroll
        for (int q = 0; q < 4; q++){
            int off = (((w*4 + ci)*4 + q)*64 + lane)*8;
            v8h bmh = *(const v8h*)(ws + WMYH_O + off);
            v8h bml = *(const v8h*)(ws + WMYL_O + off);
            v8h bfh = *(const v8h*)(ws + WFFH_O + off);
            v8h bfl = *(const v8h*)(ws + WFFL_O + off);
            #pragma unroll
            for (int rt = 0; rt < 2; rt++){
                v8h ahi = *(const v8h*)&s_hm_hi[rt*16 + l15][q*32 + quad*8];
                v8h alo = *(const v8h*)&s_hm_lo[rt*16 + l15][q*32 + quad*8];
                pre_m[ci][rt] = __builtin_amdgcn_mfma_f32_16x16x32_f16(ahi, bmh, pre_m[ci][rt],0,0,0);
                pre_m[ci][rt] = __builtin_amdgcn_mfma_f32_16x16x32_f16(ahi, bml, pre_m[ci][rt],0,0,0);
                pre_m[ci][rt] = __builtin_amdgcn_mfma_f32_16x16x32_f16(alo, bmh, pre_m[ci][rt],0,0,0);
                pre_f[ci][rt] = __builtin_amdgcn_mfma_f32_16x16x32_f16(ahi, bfh, pre_f[ci][rt],0,0,0);
                pre_f[ci][rt] = __builtin_amdgcn_mfma_f32_16x16x32_f16(ahi, bfl, pre_f[ci][rt],0,0,0);
                pre_f[ci][rt] = __builtin_amdgcn_mfma_f32_16x16x32_f16(alo, bfh, pre_f[ci][rt],0,0,0);
            }
        }
        float bmv = b_my[ci*HH + jcol], bfv = b_ff[ci*HH + jcol];
        #pragma unroll
        for (int rt = 0; rt < 2; rt++)
            #pragma unroll
            for (int v = 0; v < 4; v++){ pre_m[ci][rt][v] += bmv; pre_f[ci][rt][v] += bfv; }
    }

    // ---- persistent U B-fragments in registers (fp16 hi, permuted cols) ----
    v8h BUm[4][4], BUf[4][4];
    #pragma unroll
    for (int ci = 0; ci < 4; ci++)
        #pragma unroll
        for (int q = 0; q < 4; q++){
            int off = (((w*4 + ci)*4 + q)*64 + lane)*8;
            BUm[ci][q] = *(const v8h*)(ws + UMY_O + off);
            BUf[ci][q] = *(const v8h*)(ws + UFF_O + off);
        }

    for (int t = 0; t < TT; t++){
        v4f am[2][4];

        // ===== MFMA: z_my = pre + h_my @ U_my (A split hi/lo) =====
        #pragma unroll
        for (int rt = 0; rt < 2; rt++){
            #pragma unroll
            for (int ci = 0; ci < 4; ci++) am[rt][ci] = pre_m[ci][rt];
            #pragma unroll
            for (int q = 0; q < 4; q++){
                v8h ahi = *(const v8h*)&s_hm_hi[rt*16 + l15][q*32 + quad*8];
                v8h alo = *(const v8h*)&s_hm_lo[rt*16 + l15][q*32 + quad*8];
                #pragma unroll
                for (int ci = 0; ci < 4; ci++){
                    am[rt][ci] = __builtin_amdgcn_mfma_f32_16x16x32_f16(ahi, BUm[ci][q], am[rt][ci],0,0,0);
                    am[rt][ci] = __builtin_amdgcn_mfma_f32_16x16x32_f16(alo, BUm[ci][q], am[rt][ci],0,0,0);
                }
            }
        }
        __syncthreads();   // all A-reads of s_hm complete

        // ===== gates my (lane-local: ci = gate), write new h_my =====
        #pragma unroll
        for (int rt = 0; rt < 2; rt++)
            #pragma unroll
            for (int v = 0; v < 4; v++){
                int row = rt*16 + quad*4 + v;
                float z0 = am[rt][0][v], z1 = am[rt][1][v], z2 = am[rt][2][v], z3 = am[rt][3][v];
                #pragma unroll
                for (int k = 0; k < 5; k++){
                    float cv = s_c5[row][k];
                    z0 = fmaf(cv, s_wcm[k][0*HH + jcol], z0);
                    z1 = fmaf(cv, s_wcm[k][1*HH + jcol], z1);
                    z2 = fmaf(cv, s_wcm[k][2*HH + jcol], z2);
                    z3 = fmaf(cv, s_wcm[k][3*HH + jcol], z3);
                }
                float c2 = sigm(z1)*c_my[rt*4+v] + sigm(z0)*tanh_(z2);
                c_my[rt*4+v] = c2;
                float h = sigm(z3)*tanh_(c2);
                f16 hi = (f16)h;
                s_hm_hi[row][jcol] = hi;
                s_hm_lo[row][jcol] = (f16)(h - (float)hi);
            }

        // ===== MFMA: z_ff (reads old s_hf — no conflict with s_hm writes) =====
        #pragma unroll
        for (int rt = 0; rt < 2; rt++){
            #pragma unroll
            for (int ci = 0; ci < 4; ci++) am[rt][ci] = pre_f[ci][rt];
            #pragma unroll
            for (int q = 0; q < 4; q++){
                v8h ahi = *(const v8h*)&s_hf_hi[rt*16 + l15][q*32 + quad*8];
                v8h alo = *(const v8h*)&s_hf_lo[rt*16 + l15][q*32 + quad*8];
                #pragma unroll
                for (int ci = 0; ci < 4; ci++){
                    am[rt][ci] = __builtin_amdgcn_mfma_f32_16x16x32_f16(ahi, BUf[ci][q], am[rt][ci],0,0,0);
                    am[rt][ci] = __builtin_amdgcn_mfma_f32_16x16x32_f16(alo, BUf[ci][q], am[rt][ci],0,0,0);
                }
            }
        }
        __syncthreads();   // all A-reads of s_hf complete

        // ===== gates ff =====
        #pragma unroll
        for (int rt = 0; rt < 2; rt++)
            #pragma unroll
            for (int v = 0; v < 4; v++){
                int row = rt*16 + quad*4 + v;
                float z0 = am[rt][0][v], z1 = am[rt][1][v], z2 = am[rt][2][v], z3 = am[rt][3][v];
                #pragma unroll
                for (int k = 0; k < 2; k++){
                    float cv = s_c2[row][k];
                    z0 = fmaf(cv, s_wcf[k][0*HH + jcol], z0);
                    z1 = fmaf(cv, s_wcf[k][1*HH + jcol], z1);
                    z2 = fmaf(cv, s_wcf[k][2*HH + jcol], z2);
                    z3 = fmaf(cv, s_wcf[k][3*HH + jcol], z3);
                }
                float c2 = sigm(z1)*c_ff[rt*4+v] + sigm(z0)*tanh_(z2);
                c_ff[rt*4+v] = c2;
                float h = sigm(z3)*tanh_(c2);
                f16 hi = (f16)h;
                s_hf_hi[row][jcol] = hi;
                s_hf_lo[row][jcol] = (f16)(h - (float)hi);
            }
        __syncthreads();   // new h visible

        // ===== heads (waves 0-2: Wh_my tiles; 3-4: Wh_ff tiles) =====
        if (w < 5){
            const f16 (*Hhi)[136] = (w < 3) ? s_hm_hi : s_hf_hi;
            const f16 (*Hlo)[136] = (w < 3) ? s_hm_lo : s_hf_lo;
            int base  = (w < 3) ? WHMY_O : WHFF_O;
            int ch    = (w < 3) ? w : w - 3;
            int ncol  = (w < 3) ? 45 : 30;
            int rbase = (w < 3) ? 0 : 45;
            const float* bh = (w < 3) ? bh_my : bh_ff;
            v8h BH[4];
            #pragma unroll
            for (int q = 0; q < 4; q++)
                BH[q] = *(const v8h*)(ws + base + ((ch*4 + q)*64 + lane)*8);
            int gc = ch*16 + l15;
            #pragma unroll
            for (int rt = 0; rt < 2; rt++){
                v4f a = (v4f){0,0,0,0};
                #pragma unroll
                for (int q = 0; q < 4; q++){
                    v8h ahi = *(const v8h*)&Hhi[rt*16 + l15][q*32 + quad*8];
                    v8h alo = *(const v8h*)&Hlo[rt*16 + l15][q*32 + quad*8];
                    a = __builtin_amdgcn_mfma_f32_16x16x32_f16(ahi, BH[q], a,0,0,0);
                    a = __builtin_amdgcn_mfma_f32_16x16x32_f16(alo, BH[q], a,0,0,0);
                }
                if (gc < ncol){
                    float bias = bh[gc];
                    #pragma unroll
                    for (int v = 0; v < 4; v++)
                        s_r[rt*16 + quad*4 + v][rbase + gc] = a[v] + bias;
                }
            }
        }
        __syncthreads();

        // ===== softmax reductions =====
        if (tid < R*4){
            int r = tid >> 2, g = tid & 3;
            int base = (g==0) ? 0 : (g==1) ? 30 : (g==2) ? 45 : 60;
            float m = s_r[r][base];
            #pragma unroll
            for (int k = 1; k < KC; k++) m = fmaxf(m, s_r[r][base+k]);
            float s = 0.f;
            #pragma unroll
            for (int k = 0; k < KC; k++) s += __expf(s_r[r][base+k] - m);
            s_red[r][2*g] = m; s_red[r][2*g+1] = 1.0f / s;
        }
        __syncthreads();

        // ===== outputs (fp32) =====
        for (int idx = tid; idx < R*75; idx += NT){
            int r = idx / 75, q = idx % 75;
            int b = row0 + r;
            float v; int dst;
            if (q < 30){
                float x = s_r[r][q];
                if (q < 5)       v = __expf(x - s_red[r][0]) * s_red[r][1];
                else if (q < 10) v = x;
                else if (q < 15) v = __expf(x);
                else if (q < 20) v = x;
                else if (q < 25) v = __expf(x);
                else             v = tanh_(x);
                dst = (b*TT + t)*30 + q;
            } else if (q < 45){
                int q2 = q - 30; float x = s_r[r][30 + q2];
                v = (q2 < 5) ? __expf(x - s_red[r][2]) * s_red[r][3]
                             : (q2 < 10) ? x : __expf(x);
                dst = GY_OFF + (b*TT + t)*15 + q2;
            } else if (q < 60){
                int q2 = q - 45; float x = s_r[r][45 + q2];
                v = (q2 < 5) ? __expf(x - s_red[r][4]) * s_red[r][5]
                             : (q2 < 10) ? x : __expf(x);
                dst = GF_OFF + (b*TT + t)*15 + q2;
            } else {
                int q2 = q - 60; float x = s_r[r][60 + q2];
                v = (q2 < 5) ? __expf(x - s_red[r][6]) * s_red[r][7]
                             : (q2 < 10) ? x : __expf(x);
                dst = GFA_OFF + (b*TT + t)*15 + q2;
            }
            out[dst] = v;
        }

        // ===== sampling + next cond =====
        if (tid < R){
            int r = tid, b = row0 + r;
            int tn = (t + 1 < TT) ? t + 1 : TT - 1;
            const float* Rr = s_r[r];
            const float* g0 = gum + ((t*4 + 0)*BB + b)*KC;
            const float* g1 = gum + ((t*4 + 1)*BB + b)*KC;
            const float* g2 = gum + ((t*4 + 2)*BB + b)*KC;
            const float* g3 = gum + ((t*4 + 3)*BB + b)*KC;
            const float* zn = znorm + (t*BB + b)*5;

            int im = 0;  { float bv = Rr[0] + g0[0];
                for (int k = 1; k < KC; k++){ float v = Rr[k] + g0[k]; if (v > bv){ bv = v; im = k; } } }
            int iy = 0;  { float bv = Rr[30] + g1[0];
                for (int k = 1; k < KC; k++){ float v = Rr[30+k] + g1[k]; if (v > bv){ bv = v; iy = k; } } }
            int if_ = 0; { float bv = Rr[45] + g2[0];
                for (int k = 1; k < KC; k++){ float v = Rr[45+k] + g2[k]; if (v > bv){ bv = v; if_ = k; } } }
            int ifa = 0; { float bv = Rr[60] + g3[0];
                for (int k = 1; k < KC; k++){ float v = Rr[60+k] + g3[k]; if (v > bv){ bv = v; ifa = k; } } }

            float z1 = zn[0], z2 = zn[1];
            float rv   = tanh_(Rr[25 + im]);
            float slon = Rr[5 + im]  + __expf(Rr[10 + im]) * z1;
            float slat = Rr[15 + im] + __expf(Rr[20 + im]) *
                         (rv*z1 + sqrtf(fmaxf(0.f, 1.f - rv*rv))*z2);
            float sy  = Rr[35 + iy]  + __expf(Rr[40 + iy])  * zn[2];
            float sf  = Rr[50 + if_] + __expf(Rr[55 + if_]) * zn[3];
            float sfa = Rr[65 + ifa] + __expf(Rr[70 + ifa]) * zn[4];

            float nm0 = cond_m[(b*TT + tn)*2 + 0];
            float nm1 = cond_m[(b*TT + tn)*2 + 1];
            float ny  = cond_y[b*TT + tn];
            float nf  = cond_f[b*TT + tn];
            float nfa = cond_fa[b*TT + tn];

            float cm0 = (fabsf(slon - nm0) < AM0) ? slon : nm0;
            float cm1 = (fabsf(slat - nm1) < AM1) ? slat : nm1;
            float cy  = (fabsf(sy  - ny ) < AO ) ? sy  : ny;
            float cf  = (fabsf(sf  - nf ) < AO ) ? sf  : nf;
            float cfa = (fabsf(sfa - nfa) < AO ) ? sfa : nfa;

            s_c5[r][0] = cm0; s_c5[r][1] = cm1; s_c5[r][2] = cy;
            s_c5[r][3] = cf;  s_c5[r][4] = cfa;
            s_c2[r][0] = cf;  s_c2[r][1] = cfa;
        }
        __syncthreads();
    }
}

extern "C" void kernel_launch(void* const* d_in, const int* in_sizes, int n_in,
                              void* d_out, int out_size, void* d_ws, size_t ws_size,
                              hipStream_t stream)
{
    (void)in_sizes; (void)n_in; (void)ws_size; (void)out_size;
    const float* cond_m  = (const float*)d_in[0];
    const float* cond_y  = (const float*)d_in[1];
    const float* cond_f  = (const float*)d_in[2];
    const float* cond_fa = (const float*)d_in[3];
    const float* state_h = (const float*)d_in[4];
    const float* state_c = (const float*)d_in[5];
    const float* W_my    = (const float*)d_in[6];
    const float* U_my    = (const float*)d_in[7];
    const float* b_my    = (const float*)d_in[8];
    const float* W_ff    = (const float*)d_in[9];
    const float* U_ff    = (const float*)d_in[10];
    const float* b_ff    = (const float*)d_in[11];
    const float* Wh_my   = (const float*)d_in[12];
    const float* bh_my   = (const float*)d_in[13];
    const float* Wh_ff   = (const float*)d_in[14];
    const float* bh_ff   = (const float*)d_in[15];
    const float* gum     = (const float*)d_in[16];
    const float* znorm   = (const float*)d_in[17];
    f16* ws = (f16*)d_ws;
    float* out = (float*)d_out;

    prep_kernel<<<(PREP_N + 255)/256, 256, 0, stream>>>(U_my, U_ff, W_my, W_ff, Wh_my, Wh_ff, ws);
    decoder_kernel<<<NBLK, NT, 0, stream>>>(
        cond_m, cond_y, cond_f, cond_fa, state_h, state_c,
        W_my, b_my, W_ff, b_ff, bh_my, bh_ff, gum, znorm, ws, out);
}